// Round 1
// baseline (25014.241 us; speedup 1.0000x reference)
//
#include <hip/hip_runtime.h>
#include <hip/hip_bf16.h>

// ViT-Base/16 forward, fp32 correctness-first baseline.
// B=32, IMG=224, P=16, G=14, NPATCH=196, N=197, D=768, H=12, dh=64, MLP=3072,
// DEPTH=12, NC=1000.

#define BV   32
#define DIM  768
#define NH   12
#define DH   64
#define NSEQ 197
#define NPAT 196
#define MLPD 3072
#define NCLS 1000
#define NLAYER 12

#define TILE_M 64
#define TILE_N 64
#define TILE_K 16

// ---------------------------------------------------------------- GEMM ------
// C[M,N] = act(alpha * A[M,K] @ B + bias) (+ C_old if RESID)
// TRANSB=false: B is [K,N] row-major (ldb). TRANSB=true: B is [N,K] (ldb).
// Batched via gridDim.z with z1 = z / bdiv, z2 = z % bdiv pointer offsets.
template<bool TRANSB, int ACT, bool RESID>
__global__ __launch_bounds__(256)
void gemm_kernel(const float* __restrict__ A, const float* __restrict__ B,
                 const float* __restrict__ bias, float* __restrict__ C,
                 int M, int Ncols, int K, int lda, int ldb, int ldc,
                 int bdiv, long sA1, long sA2, long sB1, long sB2,
                 long sC1, long sC2, float alpha)
{
    __shared__ float As[TILE_K][TILE_M + 1];
    __shared__ float Bs[TILE_K][TILE_N + 1];

    int z = blockIdx.z;
    int z1 = z / bdiv, z2 = z % bdiv;
    A += (long)z1 * sA1 + (long)z2 * sA2;
    B += (long)z1 * sB1 + (long)z2 * sB2;
    C += (long)z1 * sC1 + (long)z2 * sC2;

    int tid = threadIdx.x;
    int tx = tid & 15;        // 0..15 (col group)
    int ty = tid >> 4;        // 0..15 (row group)
    int m0 = blockIdx.y * TILE_M;
    int n0 = blockIdx.x * TILE_N;

    float acc[4][4] = {};

    for (int k0 = 0; k0 < K; k0 += TILE_K) {
        // A tile: As[k][m]; load k-fastest for coalescing
        {
            int k = tid & 15;
            int mrow = tid >> 4;
            #pragma unroll
            for (int j = 0; j < 4; ++j) {
                int m = mrow + 16 * j;
                int gm = m0 + m;
                float v = 0.f;
                if (gm < M && (k0 + k) < K) v = A[(long)gm * lda + k0 + k];
                As[k][m] = v;
            }
        }
        // B tile: Bs[k][n]
        if (!TRANSB) {
            int n = tid & 63;
            int kb = tid >> 6;          // 0..3
            int gn = n0 + n;
            #pragma unroll
            for (int j = 0; j < 4; ++j) {
                int k = kb * 4 + j;
                float v = 0.f;
                if (gn < Ncols && (k0 + k) < K) v = B[(long)(k0 + k) * ldb + gn];
                Bs[k][n] = v;
            }
        } else {
            int k = tid & 15;
            int nrow = tid >> 4;
            #pragma unroll
            for (int j = 0; j < 4; ++j) {
                int n = nrow + 16 * j;
                int gn = n0 + n;
                float v = 0.f;
                if (gn < Ncols && (k0 + k) < K) v = B[(long)gn * ldb + k0 + k];
                Bs[k][n] = v;
            }
        }
        __syncthreads();

        #pragma unroll
        for (int kk = 0; kk < TILE_K; ++kk) {
            float a[4], b[4];
            #pragma unroll
            for (int i = 0; i < 4; ++i) a[i] = As[kk][ty + 16 * i];
            #pragma unroll
            for (int j = 0; j < 4; ++j) b[j] = Bs[kk][tx + 16 * j];
            #pragma unroll
            for (int i = 0; i < 4; ++i)
                #pragma unroll
                for (int j = 0; j < 4; ++j)
                    acc[i][j] += a[i] * b[j];
        }
        __syncthreads();
    }

    #pragma unroll
    for (int i = 0; i < 4; ++i) {
        int gm = m0 + ty + 16 * i;
        if (gm >= M) continue;
        #pragma unroll
        for (int j = 0; j < 4; ++j) {
            int gn = n0 + tx + 16 * j;
            if (gn >= Ncols) continue;
            float v = acc[i][j] * alpha;
            if (bias) v += bias[gn];
            if (ACT == 1) v = 0.5f * v * (1.0f + erff(v * 0.70710678118654752f));
            long idx = (long)gm * ldc + gn;
            if (RESID) v += C[idx];
            C[idx] = v;
        }
    }
}

// ---------------------------------------------------------------- LayerNorm -
__global__ __launch_bounds__(256)
void ln_kernel(const float* __restrict__ in, long in_stride,
               float* __restrict__ out, long out_stride,
               const float* __restrict__ w, const float* __restrict__ b)
{
    long r = blockIdx.x;
    const float* x = in + r * in_stride;
    float* y = out + r * out_stride;
    int tid = threadIdx.x;

    float s = 0.f, s2 = 0.f;
    for (int i = tid; i < DIM; i += 256) {
        float v = x[i];
        s += v;
        s2 += v * v;
    }
    #pragma unroll
    for (int off = 32; off > 0; off >>= 1) {
        s  += __shfl_down(s, off);
        s2 += __shfl_down(s2, off);
    }
    __shared__ float red[2][4];
    int wave = tid >> 6, lane = tid & 63;
    if (lane == 0) { red[0][wave] = s; red[1][wave] = s2; }
    __syncthreads();
    if (tid == 0) {
        float t  = red[0][0] + red[0][1] + red[0][2] + red[0][3];
        float t2 = red[1][0] + red[1][1] + red[1][2] + red[1][3];
        float mean = t / (float)DIM;
        float var  = t2 / (float)DIM - mean * mean;
        red[0][0] = mean;
        red[1][0] = 1.0f / sqrtf(var + 1e-6f);
    }
    __syncthreads();
    float mean = red[0][0], rstd = red[1][0];
    for (int i = tid; i < DIM; i += 256) {
        y[i] = (x[i] - mean) * rstd * w[i] + b[i];
    }
}

// ---------------------------------------------------------------- Softmax ---
// One wave per row of length NSEQ (197).
__global__ __launch_bounds__(64)
void softmax_kernel(float* __restrict__ sc)
{
    long r = blockIdx.x;
    float* p = sc + r * NSEQ;
    int t = threadIdx.x;

    float v[4];
    float mx = -1e30f;
    #pragma unroll
    for (int j = 0; j < 4; ++j) {
        int i = t + 64 * j;
        v[j] = (i < NSEQ) ? p[i] : -1e30f;
        mx = fmaxf(mx, v[j]);
    }
    #pragma unroll
    for (int off = 32; off > 0; off >>= 1)
        mx = fmaxf(mx, __shfl_xor(mx, off));

    float sum = 0.f;
    #pragma unroll
    for (int j = 0; j < 4; ++j) {
        v[j] = expf(v[j] - mx);   // OOB lanes: exp(-huge) == 0
        sum += v[j];
    }
    #pragma unroll
    for (int off = 32; off > 0; off >>= 1)
        sum += __shfl_xor(sum, off);

    float inv = 1.0f / sum;
    #pragma unroll
    for (int j = 0; j < 4; ++j) {
        int i = t + 64 * j;
        if (i < NSEQ) p[i] = v[j] * inv;
    }
}

// ---------------------------------------------------------------- im2col ----
// patches[b*196 + gy*14+gx][c*256 + py*16 + px] = x[b][c][gy*16+py][gx*16+px]
__global__ __launch_bounds__(256)
void im2col_kernel(const float* __restrict__ x, float* __restrict__ out)
{
    long i = (long)blockIdx.x * 256 + threadIdx.x;
    const long total = (long)BV * NPAT * DIM;
    if (i >= total) return;
    int col = (int)(i % DIM);
    long row = i / DIM;
    int c  = col >> 8;
    int py = (col >> 4) & 15;
    int px = col & 15;
    int b  = (int)(row / NPAT);
    int pp = (int)(row % NPAT);
    int gy = pp / 14, gx = pp % 14;
    out[i] = x[(((long)(b * 3 + c) * 224 + gy * 16 + py) * 224) + gx * 16 + px];
}

// ---------------------------------------------------------------- assemble --
// h[b][0][:] = cls + pos[0]; h[b][1+p][:] = tmp[b*196+p] + pos[1+p]
__global__ __launch_bounds__(256)
void assemble_kernel(const float* __restrict__ tmp, const float* __restrict__ cls,
                     const float* __restrict__ pos, float* __restrict__ h)
{
    long i = (long)blockIdx.x * 256 + threadIdx.x;
    const long total = (long)BV * NSEQ * DIM;
    if (i >= total) return;
    int d = (int)(i % DIM);
    long row = i / DIM;
    int n = (int)(row % NSEQ);
    long b = row / NSEQ;
    float v;
    if (n == 0) v = cls[d];
    else        v = tmp[(b * NPAT + (n - 1)) * DIM + d];
    h[i] = v + pos[(long)n * DIM + d];
}

// ---------------------------------------------------------------- launch ----
extern "C" void kernel_launch(void* const* d_in, const int* in_sizes, int n_in,
                              void* d_out, int out_size, void* d_ws, size_t ws_size,
                              hipStream_t stream)
{
    const float* x        = (const float*)d_in[0];
    const float* patch_w  = (const float*)d_in[1];
    const float* patch_b  = (const float*)d_in[2];
    const float* cls_tok  = (const float*)d_in[3];
    const float* pos_emb  = (const float*)d_in[4];
    const float* ln1_w    = (const float*)d_in[5];
    const float* ln1_b    = (const float*)d_in[6];
    const float* qkv_w    = (const float*)d_in[7];
    const float* qkv_b    = (const float*)d_in[8];
    const float* proj_w   = (const float*)d_in[9];
    const float* proj_b   = (const float*)d_in[10];
    const float* ln2_w    = (const float*)d_in[11];
    const float* ln2_b    = (const float*)d_in[12];
    const float* fc1_w    = (const float*)d_in[13];
    const float* fc1_b    = (const float*)d_in[14];
    const float* fc2_w    = (const float*)d_in[15];
    const float* fc2_b    = (const float*)d_in[16];
    const float* normf_w  = (const float*)d_in[17];
    const float* normf_b  = (const float*)d_in[18];
    const float* head_w   = (const float*)d_in[19];
    const float* head_b   = (const float*)d_in[20];
    float* out = (float*)d_out;

    const long M  = (long)BV * NSEQ;          // 6304
    const long MP = (long)BV * NPAT;          // 6272

    float* ws   = (float*)d_ws;
    float* h    = ws;                          // [6304, 768]
    float* buf1 = h    + M * DIM;              // [6304, 768]  (y / o / patches / cls-ln)
    float* buf2 = buf1 + M * DIM;              // [6304, 3072] (qkv / mlp)
    float* buf3 = buf2 + M * MLPD;             // [384, 197, 197] (scores / patch tmp)

    const float scale = 0.125f;                // (D/H)^-0.5 = 1/8
    dim3 blk(256);

    // ---- patch embed ----
    im2col_kernel<<<dim3((unsigned)((MP * DIM + 255) / 256)), blk, 0, stream>>>(x, buf1);
    {
        dim3 g((DIM + TILE_N - 1) / TILE_N, (MP + TILE_M - 1) / TILE_M, 1);
        gemm_kernel<false, 0, false><<<g, blk, 0, stream>>>(
            buf1, patch_w, patch_b, buf3,
            (int)MP, DIM, DIM, DIM, DIM, DIM,
            1, 0, 0, 0, 0, 0, 0, 1.0f);
    }
    assemble_kernel<<<dim3((unsigned)((M * DIM + 255) / 256)), blk, 0, stream>>>(
        buf3, cls_tok, pos_emb, h);

    // ---- transformer blocks ----
    for (int l = 0; l < NLAYER; ++l) {
        const float* l1w = ln1_w + (long)l * DIM;
        const float* l1b = ln1_b + (long)l * DIM;
        const float* qw  = qkv_w + (long)l * DIM * 3 * DIM;
        const float* qb  = qkv_b + (long)l * 3 * DIM;
        const float* pw  = proj_w + (long)l * DIM * DIM;
        const float* pb  = proj_b + (long)l * DIM;
        const float* l2w = ln2_w + (long)l * DIM;
        const float* l2b = ln2_b + (long)l * DIM;
        const float* f1w = fc1_w + (long)l * DIM * MLPD;
        const float* f1b = fc1_b + (long)l * MLPD;
        const float* f2w = fc2_w + (long)l * MLPD * DIM;
        const float* f2b = fc2_b + (long)l * DIM;

        // LN1: h -> buf1
        ln_kernel<<<dim3((unsigned)M), blk, 0, stream>>>(h, DIM, buf1, DIM, l1w, l1b);

        // QKV: buf1[6304,768] @ qw[768,2304] + qb -> buf2[6304,2304]
        {
            dim3 g((3 * DIM + TILE_N - 1) / TILE_N, (M + TILE_M - 1) / TILE_M, 1);
            gemm_kernel<false, 0, false><<<g, blk, 0, stream>>>(
                buf1, qw, qb, buf2,
                (int)M, 3 * DIM, DIM, DIM, 3 * DIM, 3 * DIM,
                1, 0, 0, 0, 0, 0, 0, 1.0f);
        }

        // scores[b,h][197,197] = scale * Q @ K^T
        {
            dim3 g((NSEQ + TILE_N - 1) / TILE_N, (NSEQ + TILE_M - 1) / TILE_M,
                   BV * NH);
            gemm_kernel<true, 0, false><<<g, blk, 0, stream>>>(
                buf2,            /* Q base */
                buf2 + DIM,      /* K base */
                nullptr, buf3,
                NSEQ, NSEQ, DH, 3 * DIM, 3 * DIM, NSEQ,
                NH,
                (long)NSEQ * 3 * DIM, DH,         /* A strides: per-b, per-h */
                (long)NSEQ * 3 * DIM, DH,         /* B strides */
                (long)NH * NSEQ * NSEQ, (long)NSEQ * NSEQ,
                scale);
        }

        // softmax rows
        softmax_kernel<<<dim3((unsigned)(BV * NH * NSEQ)), dim3(64), 0, stream>>>(buf3);

        // O[b,n,h*64+d] = scores @ V -> buf1
        {
            dim3 g((DH + TILE_N - 1) / TILE_N, (NSEQ + TILE_M - 1) / TILE_M,
                   BV * NH);
            gemm_kernel<false, 0, false><<<g, blk, 0, stream>>>(
                buf3,
                buf2 + 2 * DIM,  /* V base */
                nullptr, buf1,
                NSEQ, DH, NSEQ, NSEQ, 3 * DIM, DIM,
                NH,
                (long)NH * NSEQ * NSEQ, (long)NSEQ * NSEQ,
                (long)NSEQ * 3 * DIM, DH,
                (long)NSEQ * DIM, DH,
                1.0f);
        }

        // proj: h += buf1 @ pw + pb
        {
            dim3 g((DIM + TILE_N - 1) / TILE_N, (M + TILE_M - 1) / TILE_M, 1);
            gemm_kernel<false, 0, true><<<g, blk, 0, stream>>>(
                buf1, pw, pb, h,
                (int)M, DIM, DIM, DIM, DIM, DIM,
                1, 0, 0, 0, 0, 0, 0, 1.0f);
        }

        // LN2: h -> buf1
        ln_kernel<<<dim3((unsigned)M), blk, 0, stream>>>(h, DIM, buf1, DIM, l2w, l2b);

        // FC1 + GELU: buf1 @ f1w + f1b -> buf2[6304,3072]
        {
            dim3 g((MLPD + TILE_N - 1) / TILE_N, (M + TILE_M - 1) / TILE_M, 1);
            gemm_kernel<false, 1, false><<<g, blk, 0, stream>>>(
                buf1, f1w, f1b, buf2,
                (int)M, MLPD, DIM, DIM, MLPD, MLPD,
                1, 0, 0, 0, 0, 0, 0, 1.0f);
        }

        // FC2: h += buf2 @ f2w + f2b
        {
            dim3 g((DIM + TILE_N - 1) / TILE_N, (M + TILE_M - 1) / TILE_M, 1);
            gemm_kernel<false, 0, true><<<g, blk, 0, stream>>>(
                buf2, f2w, f2b, h,
                (int)M, DIM, MLPD, MLPD, DIM, DIM,
                1, 0, 0, 0, 0, 0, 0, 1.0f);
        }
    }

    // ---- final LN on cls rows only: h[b*197] -> buf1[b] ----
    ln_kernel<<<dim3(BV), blk, 0, stream>>>(h, (long)NSEQ * DIM, buf1, DIM,
                                            normf_w, normf_b);

    // ---- head: buf1[32,768] @ head_w[768,1000] + head_b -> out[32,1000] ----
    {
        dim3 g((NCLS + TILE_N - 1) / TILE_N, (BV + TILE_M - 1) / TILE_M, 1);
        gemm_kernel<false, 0, false><<<g, blk, 0, stream>>>(
            buf1, head_w, head_b, out,
            BV, NCLS, DIM, DIM, NCLS, NCLS,
            1, 0, 0, 0, 0, 0, 0, 1.0f);
    }
}

// Round 2
// 5607.159 us; speedup vs baseline: 4.4611x; 4.4611x over previous
//
#include <hip/hip_runtime.h>
#include <hip/hip_bf16.h>
#include <type_traits>

// ViT-Base/16 forward. Round 2: bf16 MFMA GEMMs (16x16x32), fp32 residual
// stream / LN / softmax / epilogues. m97-style 128x128 tile with
// global_load_lds width-16 staging and ds_read_b128 fragment loads.

#define BV   32
#define DIM  768
#define NHD  12
#define DH   64
#define NSEQ 197
#define NPAT 196
#define MLPD 3072
#define NCLS 1000
#define NLAYER 12

typedef __hip_bfloat16 bf16;
typedef __attribute__((ext_vector_type(8))) short s8v;    // 8 bf16 (4 VGPRs)
typedef __attribute__((ext_vector_type(4))) float f32x4;  // MFMA acc

#define GLDS16(gp, lp) __builtin_amdgcn_global_load_lds( \
    (const __attribute__((address_space(1))) void*)(gp), \
    (__attribute__((address_space(3))) void*)(lp), 16, 0, 0)

// ------------------------------------------------------------- MFMA GEMM ----
// C[M,N] = epilogue(alpha * A @ B^T + bias), A: [M,K] bf16 (lda), B: [N,K]
// bf16 (ldb) -- both K-contiguous. TO = float or bf16. ACT=1 -> exact GELU.
// RESID (TO=float only): C += result. Batched via blockIdx.z (z1=z/bdiv,
// z2=z%bdiv element strides). Requires K % 32 == 0; M,N handled with clamped
// loads + bounded stores. Tile: 128x128, BK=32, 256 threads (4 waves, 2x2).
template<int ACT, bool RESID, typename TO>
__global__ __launch_bounds__(256)
void bgemm(const bf16* __restrict__ A, const bf16* __restrict__ B,
           const float* __restrict__ bias, TO* __restrict__ C,
           int M, int N, int K, int lda, int ldb, int ldc,
           int bdiv, long sA1, long sA2, long sB1, long sB2,
           long sC1, long sC2, float alpha)
{
    __shared__ short As[4096];   // [128 rows][32 k] bf16 = 8 KB
    __shared__ short Bs[4096];

    int z = blockIdx.z;
    int z1 = z / bdiv, z2 = z % bdiv;
    A += z1 * sA1 + z2 * sA2;
    B += z1 * sB1 + z2 * sB2;
    C += z1 * sC1 + z2 * sC2;

    const int tid  = threadIdx.x;
    const int wave = tid >> 6;
    const int lane = tid & 63;
    const int m0 = blockIdx.y * 128;
    const int n0 = blockIdx.x * 128;

    // staging geometry: 8 chunks of 1024 B per tile; wave w does chunks 2w,2w+1
    // chunk c covers rows [16c,16c+16); lane l -> row 16c + l/4, kbyte (l&3)*16
    const int c0 = wave * 2, c1 = c0 + 1;
    const int rsub = lane >> 2;
    const int kp8  = (lane & 3) * 8;

    int ra0 = m0 + c0 * 16 + rsub; if (ra0 > M - 1) ra0 = M - 1;
    int ra1 = m0 + c1 * 16 + rsub; if (ra1 > M - 1) ra1 = M - 1;
    int rb0 = n0 + c0 * 16 + rsub; if (rb0 > N - 1) rb0 = N - 1;
    int rb1 = n0 + c1 * 16 + rsub; if (rb1 > N - 1) rb1 = N - 1;

    const bf16* pa0 = A + (long)ra0 * lda + kp8;
    const bf16* pa1 = A + (long)ra1 * lda + kp8;
    const bf16* pb0 = B + (long)rb0 * ldb + kp8;
    const bf16* pb1 = B + (long)rb1 * ldb + kp8;

    const int wm = wave >> 1, wn = wave & 1;
    const int colr = lane & 15;
    const int quad = lane >> 4;

    f32x4 acc[4][4];
    #pragma unroll
    for (int i = 0; i < 4; ++i)
        #pragma unroll
        for (int j = 0; j < 4; ++j)
            acc[i][j] = (f32x4){0.f, 0.f, 0.f, 0.f};

    const short* AsP = &As[(wm * 64 + colr) * 32 + quad * 8];
    const short* BsP = &Bs[(wn * 64 + colr) * 32 + quad * 8];

    for (int k0 = 0; k0 < K; k0 += 32) {
        GLDS16(pa0, &As[c0 * 512]);
        GLDS16(pa1, &As[c1 * 512]);
        GLDS16(pb0, &Bs[c0 * 512]);
        GLDS16(pb1, &Bs[c1 * 512]);
        pa0 += 32; pa1 += 32; pb0 += 32; pb1 += 32;
        __syncthreads();

        s8v a[4], b[4];
        #pragma unroll
        for (int i = 0; i < 4; ++i) a[i] = *(const s8v*)(AsP + i * 512);
        #pragma unroll
        for (int j = 0; j < 4; ++j) b[j] = *(const s8v*)(BsP + j * 512);
        #pragma unroll
        for (int i = 0; i < 4; ++i)
            #pragma unroll
            for (int j = 0; j < 4; ++j)
                acc[i][j] = __builtin_amdgcn_mfma_f32_16x16x32_bf16(
                    a[i], b[j], acc[i][j], 0, 0, 0);
        __syncthreads();
    }

    // C/D layout: col = lane&15, row = quad*4 + reg   [m89-verified]
    #pragma unroll
    for (int i = 0; i < 4; ++i) {
        int gmb = m0 + wm * 64 + i * 16 + quad * 4;
        #pragma unroll
        for (int r = 0; r < 4; ++r) {
            int gm = gmb + r;
            if (gm >= M) continue;
            #pragma unroll
            for (int j = 0; j < 4; ++j) {
                int gn = n0 + wn * 64 + j * 16 + colr;
                if (gn >= N) continue;
                float v = acc[i][j][r] * alpha;
                if (bias) v += bias[gn];
                if (ACT == 1) v = 0.5f * v * (1.0f + erff(v * 0.70710678118654752f));
                long idx = (long)gm * ldc + gn;
                if constexpr (RESID) v += ((const float*)C)[idx];
                if constexpr (std::is_same<TO, float>::value) C[idx] = v;
                else C[idx] = __float2bfloat16(v);
            }
        }
    }
}

// ------------------------------------------------- weight transpose->bf16 ---
// in: fp32 [R][C] row-major; out: bf16 [C][R].
__global__ __launch_bounds__(256)
void wconv_kernel(const float* __restrict__ in, bf16* __restrict__ out,
                  int R, int C)
{
    __shared__ float t[32][33];
    int c0 = blockIdx.x * 32, r0 = blockIdx.y * 32;
    int tx = threadIdx.x & 31, ty = threadIdx.x >> 5;
    #pragma unroll
    for (int i = 0; i < 4; ++i) {
        int r = r0 + ty + 8 * i;
        if (r < R && c0 + tx < C) t[ty + 8 * i][tx] = in[(long)r * C + c0 + tx];
    }
    __syncthreads();
    #pragma unroll
    for (int i = 0; i < 4; ++i) {
        int c = c0 + ty + 8 * i;
        int r = r0 + tx;
        if (c < C && r < R) out[(long)c * R + r] = __float2bfloat16(t[tx][ty + 8 * i]);
    }
}

// ---------------------------------------------------------------- LayerNorm -
// fp32 in -> bf16 out
__global__ __launch_bounds__(256)
void ln_kernel(const float* __restrict__ in, long in_stride,
               bf16* __restrict__ out, long out_stride,
               const float* __restrict__ w, const float* __restrict__ b)
{
    long r = blockIdx.x;
    const float* x = in + r * in_stride;
    bf16* y = out + r * out_stride;
    int tid = threadIdx.x;

    float s = 0.f, s2 = 0.f;
    for (int i = tid; i < DIM; i += 256) {
        float v = x[i];
        s += v; s2 += v * v;
    }
    #pragma unroll
    for (int off = 32; off > 0; off >>= 1) {
        s  += __shfl_down(s, off);
        s2 += __shfl_down(s2, off);
    }
    __shared__ float red[2][4];
    int wave = tid >> 6, lane = tid & 63;
    if (lane == 0) { red[0][wave] = s; red[1][wave] = s2; }
    __syncthreads();
    if (tid == 0) {
        float t  = red[0][0] + red[0][1] + red[0][2] + red[0][3];
        float t2 = red[1][0] + red[1][1] + red[1][2] + red[1][3];
        float mean = t / (float)DIM;
        float var  = t2 / (float)DIM - mean * mean;
        red[0][0] = mean;
        red[1][0] = 1.0f / sqrtf(var + 1e-6f);
    }
    __syncthreads();
    float mean = red[0][0], rstd = red[1][0];
    for (int i = tid; i < DIM; i += 256)
        y[i] = __float2bfloat16((x[i] - mean) * rstd * w[i] + b[i]);
}

// ---------------------------------------------------------------- Softmax ---
// scores: fp32 [384][197][ld=200]. Reads fp32 row, writes bf16 probs IN PLACE
// over the same bytes: bf16 row stride 400 elems (= 800 B = the fp32 row),
// 224 cols (197 real + 27 zero pad for the K=224 PV MFMA).
__global__ __launch_bounds__(64)
void softmax_kernel(float* __restrict__ scores)
{
    int R = blockIdx.x;
    int z = R / NSEQ, r = R % NSEQ;
    const float* ps = scores + (long)z * (NSEQ * 200) + (long)r * 200;
    bf16* pb = ((bf16*)scores) + (long)z * (NSEQ * 400) + (long)r * 400;
    int t = threadIdx.x;

    float v[4];
    float mx = -1e30f;
    #pragma unroll
    for (int j = 0; j < 4; ++j) {
        int i = t + 64 * j;
        v[j] = (i < NSEQ) ? ps[i] : -1e30f;
        mx = fmaxf(mx, v[j]);
    }
    #pragma unroll
    for (int off = 32; off > 0; off >>= 1)
        mx = fmaxf(mx, __shfl_xor(mx, off));

    float sum = 0.f;
    #pragma unroll
    for (int j = 0; j < 4; ++j) {
        v[j] = expf(v[j] - mx);
        sum += v[j];
    }
    #pragma unroll
    for (int off = 32; off > 0; off >>= 1)
        sum += __shfl_xor(sum, off);
    float inv = 1.0f / sum;

    #pragma unroll
    for (int j = 0; j < 4; ++j) {
        int i = t + 64 * j;
        if (i < 224) pb[i] = __float2bfloat16(i < NSEQ ? v[j] * inv : 0.f);
    }
}

// ---------------------------------------------------------------- V-transp --
// Vt[z=b*12+h][d][n(224, zero-pad)] = qkv[b*197+n][1536 + h*64 + d]
__global__ __launch_bounds__(256)
void vtrans_kernel(const bf16* __restrict__ qkv, bf16* __restrict__ Vt)
{
    long i = (long)blockIdx.x * 256 + threadIdx.x;
    const long total = 384L * DH * 224;
    if (i >= total) return;
    int n = (int)(i % 224);
    long t = i / 224;
    int d = (int)(t % DH);
    int z = (int)(t / DH);
    int b = z / NHD, hh = z % NHD;
    bf16 v = __float2bfloat16(0.f);
    if (n < NSEQ) v = qkv[(long)(b * NSEQ + n) * (3 * DIM) + 2 * DIM + hh * DH + d];
    Vt[i] = v;
}

// ---------------------------------------------------------------- im2col ----
__global__ __launch_bounds__(256)
void im2col_kernel(const float* __restrict__ x, bf16* __restrict__ out)
{
    long i = (long)blockIdx.x * 256 + threadIdx.x;
    const long total = (long)BV * NPAT * DIM;
    if (i >= total) return;
    int col = (int)(i % DIM);
    long row = i / DIM;
    int c  = col >> 8;
    int py = (col >> 4) & 15;
    int px = col & 15;
    int b  = (int)(row / NPAT);
    int pp = (int)(row % NPAT);
    int gy = pp / 14, gx = pp % 14;
    out[i] = __float2bfloat16(
        x[(((long)(b * 3 + c) * 224 + gy * 16 + py) * 224) + gx * 16 + px]);
}

// ---------------------------------------------------------------- assemble --
__global__ __launch_bounds__(256)
void assemble_kernel(const float* __restrict__ tmp, const float* __restrict__ cls,
                     const float* __restrict__ pos, float* __restrict__ h)
{
    long i = (long)blockIdx.x * 256 + threadIdx.x;
    const long total = (long)BV * NSEQ * DIM;
    if (i >= total) return;
    int d = (int)(i % DIM);
    long row = i / DIM;
    int n = (int)(row % NSEQ);
    long b = row / NSEQ;
    float v;
    if (n == 0) v = cls[d];
    else        v = tmp[(b * NPAT + (n - 1)) * DIM + d];
    h[i] = v + pos[(long)n * DIM + d];
}

// ---------------------------------------------------------------- launch ----
extern "C" void kernel_launch(void* const* d_in, const int* in_sizes, int n_in,
                              void* d_out, int out_size, void* d_ws, size_t ws_size,
                              hipStream_t stream)
{
    const float* x        = (const float*)d_in[0];
    const float* patch_w  = (const float*)d_in[1];
    const float* patch_b  = (const float*)d_in[2];
    const float* cls_tok  = (const float*)d_in[3];
    const float* pos_emb  = (const float*)d_in[4];
    const float* ln1_w    = (const float*)d_in[5];
    const float* ln1_b    = (const float*)d_in[6];
    const float* qkv_w    = (const float*)d_in[7];
    const float* qkv_b    = (const float*)d_in[8];
    const float* proj_w   = (const float*)d_in[9];
    const float* proj_b   = (const float*)d_in[10];
    const float* ln2_w    = (const float*)d_in[11];
    const float* ln2_b    = (const float*)d_in[12];
    const float* fc1_w    = (const float*)d_in[13];
    const float* fc1_b    = (const float*)d_in[14];
    const float* fc2_w    = (const float*)d_in[15];
    const float* fc2_b    = (const float*)d_in[16];
    const float* normf_w  = (const float*)d_in[17];
    const float* normf_b  = (const float*)d_in[18];
    const float* head_w   = (const float*)d_in[19];
    const float* head_b   = (const float*)d_in[20];
    float* out = (float*)d_out;

    const long M = (long)BV * NSEQ;   // 6304
    const long MP = (long)BV * NPAT;  // 6272

    // ---- workspace layout (171.5 MB total) ----
    float* h      = (float*)d_ws;                 // [6304][768] fp32
    float* scores = h + 4841472L;                 // [384][197][200] fp32 (also
                                                  //  patch-tmp fp32; probs bf16 overlay)
    bf16*  qkv    = (bf16*)(scores + 15129600L);  // [6304][2304] bf16
    bf16*  lnout  = qkv + 14524416L;              // [6304][768] bf16 (also O, head-in)
    bf16*  big    = lnout + 4841472L;             // [6304][3072] bf16 (patches/Vt/mlp)
    bf16*  wT     = big + 19365888L;              // per-layer transposed weights
    bf16*  qkvT = wT;                             // [2304][768]
    bf16*  projT = wT + 1769472L;                 // [768][768]
    bf16*  fc1T  = wT + 2359296L;                 // [3072][768]
    bf16*  fc2T  = wT + 4718592L;                 // [768][3072]

    dim3 blk(256);
    const float scale = 0.125f;

    // ---- patch embed ----
    wconv_kernel<<<dim3(24, 24), blk, 0, stream>>>(patch_w, qkvT, DIM, DIM);
    im2col_kernel<<<dim3((unsigned)((MP * DIM + 255) / 256)), blk, 0, stream>>>(x, big);
    bgemm<0, false, float><<<dim3(6, 49, 1), blk, 0, stream>>>(
        big, qkvT, patch_b, scores,
        (int)MP, DIM, DIM, DIM, DIM, DIM,
        1, 0, 0, 0, 0, 0, 0, 1.0f);
    assemble_kernel<<<dim3((unsigned)((M * DIM + 255) / 256)), blk, 0, stream>>>(
        scores, cls_tok, pos_emb, h);

    // ---- transformer blocks ----
    for (int l = 0; l < NLAYER; ++l) {
        // weights -> bf16 [N][K]
        wconv_kernel<<<dim3(72, 24), blk, 0, stream>>>(
            qkv_w + (long)l * DIM * 3 * DIM, qkvT, DIM, 3 * DIM);
        wconv_kernel<<<dim3(24, 24), blk, 0, stream>>>(
            proj_w + (long)l * DIM * DIM, projT, DIM, DIM);
        wconv_kernel<<<dim3(96, 24), blk, 0, stream>>>(
            fc1_w + (long)l * DIM * MLPD, fc1T, DIM, MLPD);
        wconv_kernel<<<dim3(24, 96), blk, 0, stream>>>(
            fc2_w + (long)l * MLPD * DIM, fc2T, MLPD, DIM);

        // LN1: h -> lnout (bf16)
        ln_kernel<<<dim3((unsigned)M), blk, 0, stream>>>(
            h, DIM, lnout, DIM, ln1_w + (long)l * DIM, ln1_b + (long)l * DIM);

        // QKV: lnout @ qkvT^T + qb -> qkv (bf16)
        bgemm<0, false, bf16><<<dim3(18, 50, 1), blk, 0, stream>>>(
            lnout, qkvT, qkv_b + (long)l * 3 * DIM, qkv,
            (int)M, 3 * DIM, DIM, DIM, DIM, 3 * DIM,
            1, 0, 0, 0, 0, 0, 0, 1.0f);

        // scores = 0.125 * Q @ K^T  (fp32, ld 200), z = b*12+h
        bgemm<0, false, float><<<dim3(2, 2, BV * NHD), blk, 0, stream>>>(
            qkv,            /* Q */
            qkv + DIM,      /* K */
            nullptr, scores,
            NSEQ, NSEQ, DH, 3 * DIM, 3 * DIM, 200,
            NHD,
            (long)NSEQ * 3 * DIM, DH,
            (long)NSEQ * 3 * DIM, DH,
            (long)NHD * NSEQ * 200, (long)NSEQ * 200,
            scale);

        // softmax in place -> bf16 probs (ld 400, 224 cols, zero-padded)
        softmax_kernel<<<dim3(BV * NHD * NSEQ), dim3(64), 0, stream>>>(scores);

        // Vt[z][64][224] (zero-padded)
        vtrans_kernel<<<dim3((unsigned)((384L * DH * 224 + 255) / 256)), blk, 0,
                        stream>>>(qkv, big);

        // O = probs @ Vt^T -> lnout region (bf16), C[b][n][h*64+d]
        bgemm<0, false, bf16><<<dim3(1, 2, BV * NHD), blk, 0, stream>>>(
            (const bf16*)scores, big, nullptr, lnout,
            NSEQ, DH, 224, 400, 224, DIM,
            NHD,
            (long)NHD * NSEQ * 400, (long)NSEQ * 400,
            (long)NHD * DH * 224, (long)DH * 224,
            (long)NSEQ * DIM, DH,
            1.0f);

        // proj: h += O @ projT^T + pb
        bgemm<0, true, float><<<dim3(6, 50, 1), blk, 0, stream>>>(
            lnout, projT, proj_b + (long)l * DIM, h,
            (int)M, DIM, DIM, DIM, DIM, DIM,
            1, 0, 0, 0, 0, 0, 0, 1.0f);

        // LN2: h -> lnout (bf16)
        ln_kernel<<<dim3((unsigned)M), blk, 0, stream>>>(
            h, DIM, lnout, DIM, ln2_w + (long)l * DIM, ln2_b + (long)l * DIM);

        // FC1 + GELU -> mlp (bf16, big region)
        bgemm<1, false, bf16><<<dim3(24, 50, 1), blk, 0, stream>>>(
            lnout, fc1T, fc1_b + (long)l * MLPD, big,
            (int)M, MLPD, DIM, DIM, DIM, MLPD,
            1, 0, 0, 0, 0, 0, 0, 1.0f);

        // FC2: h += mlp @ fc2T^T + f2b
        bgemm<0, true, float><<<dim3(6, 50, 1), blk, 0, stream>>>(
            big, fc2T, fc2_b + (long)l * DIM, h,
            (int)M, DIM, MLPD, MLPD, MLPD, DIM,
            1, 0, 0, 0, 0, 0, 0, 1.0f);
    }

    // ---- final LN on cls rows -> lnout[0:32] (bf16) ----
    ln_kernel<<<dim3(BV), blk, 0, stream>>>(
        h, (long)NSEQ * DIM, lnout, DIM, normf_w, normf_b);

    // ---- head ----
    wconv_kernel<<<dim3(32, 24), blk, 0, stream>>>(head_w, qkvT, DIM, NCLS);
    bgemm<0, false, float><<<dim3(8, 1, 1), blk, 0, stream>>>(
        lnout, qkvT, head_b, out,
        BV, NCLS, DIM, DIM, DIM, NCLS,
        1, 0, 0, 0, 0, 0, 0, 1.0f);
}

// Round 3
// 3869.333 us; speedup vs baseline: 6.4647x; 1.4491x over previous
//
#include <hip/hip_runtime.h>
#include <hip/hip_bf16.h>
#include <type_traits>

// ViT-Base/16 forward. Round 3: vectorized LDS-transpose epilogue, XCD-aware
// tile swizzle, fused flash-style attention (replaces scores/softmax/vtrans/PV).

#define BV   32
#define DIM  768
#define NHD  12
#define DH   64
#define NSEQ 197
#define NPAT 196
#define MLPD 3072
#define NCLS 1000
#define NLAYER 12

typedef __hip_bfloat16 bf16;
typedef __attribute__((ext_vector_type(8))) short s8v;    // 8 bf16 (4 VGPRs)
typedef __attribute__((ext_vector_type(4))) float f32x4;  // MFMA acc

#define GLDS16(gp, lp) __builtin_amdgcn_global_load_lds( \
    (const __attribute__((address_space(1))) void*)(gp), \
    (__attribute__((address_space(3))) void*)(lp), 16, 0, 0)

__device__ __forceinline__ short f2bf(float v) {
    return (short)__bfloat16_as_ushort(__float2bfloat16(v));
}

// ------------------------------------------------------------- MFMA GEMM ----
// C[M,N] = epilogue(A @ B^T + bias), A: [M,K] bf16 (lda), B: [N,K] bf16 (ldb),
// both K-contiguous. TO = float or bf16. ACT=1 -> exact GELU. RESID (float
// only): C += result. K % 32 == 0. Tile 128x128, BK=32, 4 waves (2x2).
template<int ACT, bool RESID, typename TO>
__global__ __launch_bounds__(256)
void bgemm(const bf16* __restrict__ A, const bf16* __restrict__ B,
           const float* __restrict__ bias, TO* __restrict__ C,
           int M, int N, int K, int lda, int ldb, int ldc)
{
    __shared__ short As[8192];               // [0:4096)=A tile, [4096:8192)=B tile

    // XCD-aware swizzle: balanced bijection, XCD x owns a contiguous
    // row-major tile range (shares A panels, streams B).
    int nbx = gridDim.x;
    int nb  = nbx * gridDim.y;
    int bid = blockIdx.y * nbx + blockIdx.x;
    {
        int per = nb >> 3, rem = nb & 7;
        int x = bid & 7, loc = bid >> 3;
        bid = x * per + (x < rem ? x : rem) + loc;
    }
    const int m0 = (bid / nbx) * 128;
    const int n0 = (bid % nbx) * 128;

    const int tid  = threadIdx.x;
    const int wave = tid >> 6;
    const int lane = tid & 63;

    const int c0 = wave * 2, c1 = c0 + 1;
    const int rsub = lane >> 2;
    const int kp8  = (lane & 3) * 8;

    int ra0 = m0 + c0 * 16 + rsub; if (ra0 > M - 1) ra0 = M - 1;
    int ra1 = m0 + c1 * 16 + rsub; if (ra1 > M - 1) ra1 = M - 1;
    int rb0 = n0 + c0 * 16 + rsub; if (rb0 > N - 1) rb0 = N - 1;
    int rb1 = n0 + c1 * 16 + rsub; if (rb1 > N - 1) rb1 = N - 1;

    const bf16* pa0 = A + (long)ra0 * lda + kp8;
    const bf16* pa1 = A + (long)ra1 * lda + kp8;
    const bf16* pb0 = B + (long)rb0 * ldb + kp8;
    const bf16* pb1 = B + (long)rb1 * ldb + kp8;

    const int wm = wave >> 1, wn = wave & 1;
    const int colr = lane & 15;
    const int quad = lane >> 4;

    f32x4 acc[4][4];
    #pragma unroll
    for (int i = 0; i < 4; ++i)
        #pragma unroll
        for (int j = 0; j < 4; ++j)
            acc[i][j] = (f32x4){0.f, 0.f, 0.f, 0.f};

    const short* AsP = &As[(wm * 64 + colr) * 32 + quad * 8];
    const short* BsP = &As[4096 + (wn * 64 + colr) * 32 + quad * 8];

    for (int k0 = 0; k0 < K; k0 += 32) {
        GLDS16(pa0, &As[c0 * 512]);
        GLDS16(pa1, &As[c1 * 512]);
        GLDS16(pb0, &As[4096 + c0 * 512]);
        GLDS16(pb1, &As[4096 + c1 * 512]);
        pa0 += 32; pa1 += 32; pb0 += 32; pb1 += 32;
        __syncthreads();

        s8v a[4], b[4];
        #pragma unroll
        for (int i = 0; i < 4; ++i) a[i] = *(const s8v*)(AsP + i * 512);
        #pragma unroll
        for (int j = 0; j < 4; ++j) b[j] = *(const s8v*)(BsP + j * 512);
        #pragma unroll
        for (int i = 0; i < 4; ++i)
            #pragma unroll
            for (int j = 0; j < 4; ++j)
                acc[i][j] = __builtin_amdgcn_mfma_f32_16x16x32_bf16(
                    a[i], b[j], acc[i][j], 0, 0, 0);
        __syncthreads();
    }

    // ---- epilogue: per-wave LDS transpose -> vectorized stores ----
    // C/D layout: col = lane&15, row = quad*4 + reg   [m89-verified]
    float* ep = ((float*)As) + wave * 1024;   // 16x64 fp32 per wave (16 KB tot)
    const int lrow = lane >> 2;
    const int lc4  = (lane & 3) * 16;

    #pragma unroll
    for (int i = 0; i < 4; ++i) {
        #pragma unroll
        for (int j = 0; j < 4; ++j)
            #pragma unroll
            for (int r = 0; r < 4; ++r)
                ep[(quad * 4 + r) * 64 + j * 16 + colr] = acc[i][j][r];
        __syncthreads();

        int gm = m0 + wm * 64 + i * 16 + lrow;
        int gn = n0 + wn * 64 + lc4;
        if (gm < M) {
            float vals[16];
            #pragma unroll
            for (int c = 0; c < 16; ++c) vals[c] = ep[lrow * 64 + lc4 + c];

            if (gn + 16 <= N) {
                if (bias) {
                    #pragma unroll
                    for (int c = 0; c < 16; ++c) vals[c] += bias[gn + c];
                }
                if (ACT == 1) {
                    #pragma unroll
                    for (int c = 0; c < 16; ++c)
                        vals[c] = 0.5f * vals[c] *
                                  (1.0f + erff(vals[c] * 0.70710678118654752f));
                }
                if constexpr (std::is_same<TO, float>::value) {
                    float* Cp = (float*)C + (long)gm * ldc + gn;
                    if constexpr (RESID) {
                        #pragma unroll
                        for (int c4 = 0; c4 < 4; ++c4) {
                            f32x4 old = *(const f32x4*)&Cp[c4 * 4];
                            #pragma unroll
                            for (int e = 0; e < 4; ++e) vals[c4 * 4 + e] += old[e];
                        }
                    }
                    #pragma unroll
                    for (int c4 = 0; c4 < 4; ++c4) {
                        f32x4 v; 
                        #pragma unroll
                        for (int e = 0; e < 4; ++e) v[e] = vals[c4 * 4 + e];
                        *(f32x4*)&Cp[c4 * 4] = v;
                    }
                } else {
                    short* Cp = (short*)C + (long)gm * ldc + gn;
                    s8v v0, v1;
                    #pragma unroll
                    for (int e = 0; e < 8; ++e) { v0[e] = f2bf(vals[e]); v1[e] = f2bf(vals[8 + e]); }
                    *(s8v*)&Cp[0] = v0;
                    *(s8v*)&Cp[8] = v1;
                }
            } else {
                // partial-N fallback (head GEMM, N=1000)
                #pragma unroll
                for (int c = 0; c < 16; ++c) {
                    int g = gn + c;
                    if (g >= N) continue;
                    float v = vals[c];
                    if (bias) v += bias[g];
                    if (ACT == 1) v = 0.5f * v * (1.0f + erff(v * 0.70710678118654752f));
                    long idx = (long)gm * ldc + g;
                    if constexpr (RESID) v += ((const float*)C)[idx];
                    if constexpr (std::is_same<TO, float>::value) C[idx] = v;
                    else C[idx] = __float2bfloat16(v);
                }
            }
        }
        __syncthreads();
    }
}

// --------------------------------------------------- fused flash attention --
// One WG (4 waves) per (b, h, 64-row Q tile). qkv: [B*197][2304] bf16
// (q|k|v, head-contig 64). O: [B*197][768] bf16.
__global__ __launch_bounds__(256)
void attn_kernel(const bf16* __restrict__ qkv, bf16* __restrict__ O)
{
    __shared__ short Qs[64 * 72];    // +8 pad: kills 16-way frag-read conflicts
    __shared__ short Ks[224 * 72];   // P (64x224) overlays after S-phase
    __shared__ short Vt[64 * 224];   // V transposed [d][seq]

    const int tid  = threadIdx.x;
    const int wave = tid >> 6;
    const int lane = tid & 63;
    const int q0 = blockIdx.x * 64;
    const int b  = blockIdx.y / NHD;
    const int h  = blockIdx.y % NHD;
    const bf16* base = qkv + (long)b * NSEQ * (3 * DIM);

    // ---- stage Q (64x64), K (224x64, clamped), Vt (64x224, clamped) ----
    #pragma unroll
    for (int p = 0; p < 2; ++p) {
        int idx = p * 2048 + tid * 8;
        int row = idx >> 6, col = idx & 63;
        int gr = q0 + row; if (gr > NSEQ - 1) gr = NSEQ - 1;
        *(s8v*)&Qs[row * 72 + col] =
            *(const s8v*)&base[(long)gr * (3 * DIM) + h * DH + col];
    }
    #pragma unroll
    for (int p = 0; p < 7; ++p) {
        int idx = p * 2048 + tid * 8;
        int row = idx >> 6, col = idx & 63;
        int gr = row; if (gr > NSEQ - 1) gr = NSEQ - 1;
        *(s8v*)&Ks[row * 72 + col] =
            *(const s8v*)&base[(long)gr * (3 * DIM) + DIM + h * DH + col];
    }
    {
        int seqL = tid & 31, dc = tid >> 5;   // dc 0..7
        #pragma unroll
        for (int st = 0; st < 7; ++st) {
            int seq = st * 32 + seqL;
            int gr = seq; if (gr > NSEQ - 1) gr = NSEQ - 1;
            s8v v = *(const s8v*)&base[(long)gr * (3 * DIM) + 2 * DIM + h * DH + dc * 8];
            #pragma unroll
            for (int i = 0; i < 8; ++i)
                Vt[(dc * 8 + i) * 224 + seq] = v[i];
        }
    }
    __syncthreads();

    const int colr = lane & 15;
    const int quad = lane >> 4;

    // ---- S = Q @ K^T : each wave = 16 rows x 224 cols, K=64 ----
    f32x4 s[14];
    #pragma unroll
    for (int j = 0; j < 14; ++j) s[j] = (f32x4){0.f, 0.f, 0.f, 0.f};
    #pragma unroll
    for (int kk = 0; kk < 2; ++kk) {
        s8v a = *(const s8v*)&Qs[(wave * 16 + colr) * 72 + quad * 8 + kk * 32];
        #pragma unroll
        for (int j = 0; j < 14; ++j) {
            s8v bf = *(const s8v*)&Ks[(j * 16 + colr) * 72 + quad * 8 + kk * 32];
            s[j] = __builtin_amdgcn_mfma_f32_16x16x32_bf16(a, bf, s[j], 0, 0, 0);
        }
    }

    // ---- softmax (rows: quad*4+r within wave slice; col: j*16+colr) ----
    float mx[4] = {-1e30f, -1e30f, -1e30f, -1e30f};
    #pragma unroll
    for (int j = 0; j < 14; ++j) {
        int c = j * 16 + colr;
        #pragma unroll
        for (int r = 0; r < 4; ++r) {
            s[j][r] *= 0.125f;
            if (c < NSEQ) mx[r] = fmaxf(mx[r], s[j][r]);
        }
    }
    #pragma unroll
    for (int off = 1; off <= 8; off <<= 1)
        #pragma unroll
        for (int r = 0; r < 4; ++r)
            mx[r] = fmaxf(mx[r], __shfl_xor(mx[r], off));

    float sum[4] = {0.f, 0.f, 0.f, 0.f};
    #pragma unroll
    for (int j = 0; j < 14; ++j) {
        int c = j * 16 + colr;
        #pragma unroll
        for (int r = 0; r < 4; ++r) {
            float v = (c < NSEQ) ? expf(s[j][r] - mx[r]) : 0.f;
            s[j][r] = v;
            sum[r] += v;
        }
    }
    #pragma unroll
    for (int off = 1; off <= 8; off <<= 1)
        #pragma unroll
        for (int r = 0; r < 4; ++r)
            sum[r] += __shfl_xor(sum[r], off);
    float inv[4];
    #pragma unroll
    for (int r = 0; r < 4; ++r) inv[r] = 1.0f / sum[r];

    __syncthreads();                 // all waves done reading Ks
    short* P = Ks;                   // overlay: [64 rows][224 k] bf16
    #pragma unroll
    for (int j = 0; j < 14; ++j)
        #pragma unroll
        for (int r = 0; r < 4; ++r)
            P[(wave * 16 + quad * 4 + r) * 224 + j * 16 + colr] =
                f2bf(s[j][r] * inv[r]);

    // ---- O = P @ V : per wave 16 rows x 64 dims, K=224 ----
    f32x4 o[4];
    #pragma unroll
    for (int j2 = 0; j2 < 4; ++j2) o[j2] = (f32x4){0.f, 0.f, 0.f, 0.f};
    #pragma unroll
    for (int ks = 0; ks < 7; ++ks) {
        s8v a = *(const s8v*)&P[(wave * 16 + colr) * 224 + quad * 8 + ks * 32];
        #pragma unroll
        for (int j2 = 0; j2 < 4; ++j2) {
            s8v bf = *(const s8v*)&Vt[(j2 * 16 + colr) * 224 + quad * 8 + ks * 32];
            o[j2] = __builtin_amdgcn_mfma_f32_16x16x32_bf16(a, bf, o[j2], 0, 0, 0);
        }
    }

    #pragma unroll
    for (int j2 = 0; j2 < 4; ++j2)
        #pragma unroll
        for (int r = 0; r < 4; ++r) {
            int qrow = q0 + wave * 16 + quad * 4 + r;
            if (qrow < NSEQ)
                O[((long)b * NSEQ + qrow) * DIM + h * DH + j2 * 16 + colr] =
                    __float2bfloat16(o[j2][r]);
        }
}

// ------------------------------------------------- weight transpose->bf16 ---
__global__ __launch_bounds__(256)
void wconv_kernel(const float* __restrict__ in, bf16* __restrict__ out,
                  int R, int C)
{
    __shared__ float t[32][33];
    int c0 = blockIdx.x * 32, r0 = blockIdx.y * 32;
    int tx = threadIdx.x & 31, ty = threadIdx.x >> 5;
    #pragma unroll
    for (int i = 0; i < 4; ++i) {
        int r = r0 + ty + 8 * i;
        if (r < R && c0 + tx < C) t[ty + 8 * i][tx] = in[(long)r * C + c0 + tx];
    }
    __syncthreads();
    #pragma unroll
    for (int i = 0; i < 4; ++i) {
        int c = c0 + ty + 8 * i;
        int r = r0 + tx;
        if (c < C && r < R) out[(long)c * R + r] = __float2bfloat16(t[tx][ty + 8 * i]);
    }
}

// ---------------------------------------------------------------- LayerNorm -
__global__ __launch_bounds__(256)
void ln_kernel(const float* __restrict__ in, long in_stride,
               bf16* __restrict__ out, long out_stride,
               const float* __restrict__ w, const float* __restrict__ b)
{
    long r = blockIdx.x;
    const float* x = in + r * in_stride;
    bf16* y = out + r * out_stride;
    int tid = threadIdx.x;

    float s = 0.f, s2 = 0.f;
    for (int i = tid; i < DIM; i += 256) {
        float v = x[i];
        s += v; s2 += v * v;
    }
    #pragma unroll
    for (int off = 32; off > 0; off >>= 1) {
        s  += __shfl_down(s, off);
        s2 += __shfl_down(s2, off);
    }
    __shared__ float red[2][4];
    int wave = tid >> 6, lane = tid & 63;
    if (lane == 0) { red[0][wave] = s; red[1][wave] = s2; }
    __syncthreads();
    if (tid == 0) {
        float t  = red[0][0] + red[0][1] + red[0][2] + red[0][3];
        float t2 = red[1][0] + red[1][1] + red[1][2] + red[1][3];
        float mean = t / (float)DIM;
        float var  = t2 / (float)DIM - mean * mean;
        red[0][0] = mean;
        red[1][0] = 1.0f / sqrtf(var + 1e-6f);
    }
    __syncthreads();
    float mean = red[0][0], rstd = red[1][0];
    for (int i = tid; i < DIM; i += 256)
        y[i] = __float2bfloat16((x[i] - mean) * rstd * w[i] + b[i]);
}

// ---------------------------------------------------------------- im2col ----
__global__ __launch_bounds__(256)
void im2col_kernel(const float* __restrict__ x, bf16* __restrict__ out)
{
    long i = (long)blockIdx.x * 256 + threadIdx.x;
    const long total = (long)BV * NPAT * DIM;
    if (i >= total) return;
    int col = (int)(i % DIM);
    long row = i / DIM;
    int c  = col >> 8;
    int py = (col >> 4) & 15;
    int px = col & 15;
    int b  = (int)(row / NPAT);
    int pp = (int)(row % NPAT);
    int gy = pp / 14, gx = pp % 14;
    out[i] = __float2bfloat16(
        x[(((long)(b * 3 + c) * 224 + gy * 16 + py) * 224) + gx * 16 + px]);
}

// ---------------------------------------------------------------- assemble --
__global__ __launch_bounds__(256)
void assemble_kernel(const float* __restrict__ tmp, const float* __restrict__ cls,
                     const float* __restrict__ pos, float* __restrict__ h)
{
    long i = (long)blockIdx.x * 256 + threadIdx.x;
    const long total = (long)BV * NSEQ * DIM;
    if (i >= total) return;
    int d = (int)(i % DIM);
    long row = i / DIM;
    int n = (int)(row % NSEQ);
    long b = row / NSEQ;
    float v;
    if (n == 0) v = cls[d];
    else        v = tmp[(b * NPAT + (n - 1)) * DIM + d];
    h[i] = v + pos[(long)n * DIM + d];
}

// ---------------------------------------------------------------- launch ----
extern "C" void kernel_launch(void* const* d_in, const int* in_sizes, int n_in,
                              void* d_out, int out_size, void* d_ws, size_t ws_size,
                              hipStream_t stream)
{
    const float* x        = (const float*)d_in[0];
    const float* patch_w  = (const float*)d_in[1];
    const float* patch_b  = (const float*)d_in[2];
    const float* cls_tok  = (const float*)d_in[3];
    const float* pos_emb  = (const float*)d_in[4];
    const float* ln1_w    = (const float*)d_in[5];
    const float* ln1_b    = (const float*)d_in[6];
    const float* qkv_w    = (const float*)d_in[7];
    const float* qkv_b    = (const float*)d_in[8];
    const float* proj_w   = (const float*)d_in[9];
    const float* proj_b   = (const float*)d_in[10];
    const float* ln2_w    = (const float*)d_in[11];
    const float* ln2_b    = (const float*)d_in[12];
    const float* fc1_w    = (const float*)d_in[13];
    const float* fc1_b    = (const float*)d_in[14];
    const float* fc2_w    = (const float*)d_in[15];
    const float* fc2_b    = (const float*)d_in[16];
    const float* normf_w  = (const float*)d_in[17];
    const float* normf_b  = (const float*)d_in[18];
    const float* head_w   = (const float*)d_in[19];
    const float* head_b   = (const float*)d_in[20];
    float* out = (float*)d_out;

    const long M = (long)BV * NSEQ;   // 6304
    const long MP = (long)BV * NPAT;  // 6272

    // ---- workspace layout ----
    float* h      = (float*)d_ws;                 // [6304][768] fp32
    float* ptmp   = h + 4841472L;                 // patch-embed tmp fp32 [6272][768]
    bf16*  qkv    = (bf16*)(ptmp + 4816896L);     // [6304][2304] bf16
    bf16*  lnout  = qkv + 14524416L;              // [6304][768] bf16 (ln out / O)
    bf16*  big    = lnout + 4841472L;             // [6304][3072] bf16 (patches/mlp)
    bf16*  wT     = big + 19365888L;              // per-layer transposed weights
    bf16*  qkvT = wT;                             // [2304][768]
    bf16*  projT = wT + 1769472L;                 // [768][768]
    bf16*  fc1T  = wT + 2359296L;                 // [3072][768]
    bf16*  fc2T  = wT + 4718592L;                 // [768][3072]

    dim3 blk(256);

    // ---- patch embed ----
    wconv_kernel<<<dim3(24, 24), blk, 0, stream>>>(patch_w, qkvT, DIM, DIM);
    im2col_kernel<<<dim3((unsigned)((MP * DIM + 255) / 256)), blk, 0, stream>>>(x, big);
    bgemm<0, false, float><<<dim3(6, 49), blk, 0, stream>>>(
        big, qkvT, patch_b, ptmp, (int)MP, DIM, DIM, DIM, DIM, DIM);
    assemble_kernel<<<dim3((unsigned)((M * DIM + 255) / 256)), blk, 0, stream>>>(
        ptmp, cls_tok, pos_emb, h);

    // ---- transformer blocks ----
    for (int l = 0; l < NLAYER; ++l) {
        wconv_kernel<<<dim3(72, 24), blk, 0, stream>>>(
            qkv_w + (long)l * DIM * 3 * DIM, qkvT, DIM, 3 * DIM);
        wconv_kernel<<<dim3(24, 24), blk, 0, stream>>>(
            proj_w + (long)l * DIM * DIM, projT, DIM, DIM);
        wconv_kernel<<<dim3(96, 24), blk, 0, stream>>>(
            fc1_w + (long)l * DIM * MLPD, fc1T, DIM, MLPD);
        wconv_kernel<<<dim3(24, 96), blk, 0, stream>>>(
            fc2_w + (long)l * MLPD * DIM, fc2T, MLPD, DIM);

        // LN1: h -> lnout (bf16)
        ln_kernel<<<dim3((unsigned)M), blk, 0, stream>>>(
            h, DIM, lnout, DIM, ln1_w + (long)l * DIM, ln1_b + (long)l * DIM);

        // QKV: lnout @ qkvT^T + qb -> qkv (bf16)
        bgemm<0, false, bf16><<<dim3(18, 50), blk, 0, stream>>>(
            lnout, qkvT, qkv_b + (long)l * 3 * DIM, qkv,
            (int)M, 3 * DIM, DIM, DIM, DIM, 3 * DIM);

        // fused attention -> lnout (bf16 O)
        attn_kernel<<<dim3(4, BV * NHD), blk, 0, stream>>>(qkv, lnout);

        // proj: h += O @ projT^T + pb
        bgemm<0, true, float><<<dim3(6, 50), blk, 0, stream>>>(
            lnout, projT, proj_b + (long)l * DIM, h,
            (int)M, DIM, DIM, DIM, DIM, DIM);

        // LN2: h -> lnout (bf16)
        ln_kernel<<<dim3((unsigned)M), blk, 0, stream>>>(
            h, DIM, lnout, DIM, ln2_w + (long)l * DIM, ln2_b + (long)l * DIM);

        // FC1 + GELU -> big (bf16)
        bgemm<1, false, bf16><<<dim3(24, 50), blk, 0, stream>>>(
            lnout, fc1T, fc1_b + (long)l * MLPD, big,
            (int)M, MLPD, DIM, DIM, DIM, MLPD);

        // FC2: h += big @ fc2T^T + f2b
        bgemm<0, true, float><<<dim3(6, 50), blk, 0, stream>>>(
            big, fc2T, fc2_b + (long)l * DIM, h,
            (int)M, DIM, MLPD, MLPD, MLPD, DIM);
    }

    // ---- final LN on cls rows -> lnout[0:32] (bf16) ----
    ln_kernel<<<dim3(BV), blk, 0, stream>>>(
        h, (long)NSEQ * DIM, lnout, DIM, normf_w, normf_b);

    // ---- head ----
    wconv_kernel<<<dim3(32, 24), blk, 0, stream>>>(head_w, qkvT, DIM, NCLS);
    bgemm<0, false, float><<<dim3(8, 1), blk, 0, stream>>>(
        lnout, qkvT, head_b, out, BV, NCLS, DIM, DIM, DIM, NCLS);
}